// Round 13
// baseline (154.336 us; speedup 1.0000x reference)
//
#include <hip/hip_runtime.h>
#include <math.h>

#define D 128
#define EPS 1e-30f
#define LN_EPS 1e-5f

#define BINSHIFT 8
#define BINW 256
#define NBIN_MAX 256
#define P1_EPB 2048

typedef long long ll;
typedef __attribute__((ext_vector_type(8))) short short8;
typedef __attribute__((ext_vector_type(4))) float f32x4;
typedef __attribute__((ext_vector_type(2))) float f32x2;

#if __has_builtin(__builtin_amdgcn_cvt_pk_f32_fp8) && __has_builtin(__builtin_amdgcn_cvt_pk_fp8_f32)
#define HAS_FP8_CVT 1
#else
#define HAS_FP8_CVT 0
#endif

// round-to-nearest-even f32 -> bf16
__device__ inline unsigned short f2bf(float f) {
    unsigned int u = __float_as_uint(f);
    u += 0x7FFF + ((u >> 16) & 1);
    return (unsigned short)(u >> 16);
}

__device__ inline float bf2f_lo(unsigned int w) { return __uint_as_float(w << 16); }
__device__ inline float bf2f_hi(unsigned int w) { return __uint_as_float(w & 0xFFFF0000u); }

// ---- fp8 e4m3 helpers (positive values only: exp(x) > 0) ----
__device__ inline unsigned int pack_fp8x4(float f0, float f1, float f2, float f3) {
#if HAS_FP8_CVT
    int p = 0;
    p = __builtin_amdgcn_cvt_pk_fp8_f32(fminf(f0, 440.f), fminf(f1, 440.f), p, false);
    p = __builtin_amdgcn_cvt_pk_fp8_f32(fminf(f2, 440.f), fminf(f3, 440.f), p, true);
    return (unsigned int)p;
#else
    auto enc = [](float f) -> unsigned int {
        if (!(f > 1.7e-3f)) return (unsigned int)max(0, min(7, (int)rintf(f * 512.f)));
        f = fminf(f, 440.f);
        unsigned int u = __float_as_uint(f);
        int ex = (int)((u >> 23) & 255) - 127;
        if (ex < -6) return (unsigned int)min(7, (int)rintf(f * 512.f));
        unsigned int mant = u & 0x7FFFFF;
        unsigned int r = (mant + 0x7FFFF + ((mant >> 20) & 1)) >> 20;
        return (unsigned int)(((ex + 7) << 3) + r);
    };
    return enc(f0) | (enc(f1) << 8) | (enc(f2) << 16) | (enc(f3) << 24);
#endif
}

__device__ inline void acc_fp8x4(unsigned int u, float* acc) {
#if HAS_FP8_CVT
    f32x2 a = __builtin_amdgcn_cvt_pk_f32_fp8((int)u, false);
    f32x2 b = __builtin_amdgcn_cvt_pk_f32_fp8((int)u, true);
    acc[0] += a[0]; acc[1] += a[1]; acc[2] += b[0]; acc[3] += b[1];
#else
    auto dec = [](unsigned int v) -> float {
        unsigned int e = (v >> 3) & 15, m = v & 7;
        if (e == 0) return (float)m * 0.001953125f;
        return __uint_as_float(((e + 120) << 23) | (m << 20));
    };
    acc[0] += dec(u & 255); acc[1] += dec((u >> 8) & 255);
    acc[2] += dec((u >> 16) & 255); acc[3] += dec(u >> 24);
#endif
}

// ---- index dtype sniffing: harness may hand us int32 or int64 indices ----
__device__ inline bool idx_is_i64(const void* p, int n_nodes) {
    const ll* q = (const ll*)p;
    bool ok = true;
#pragma unroll
    for (int i = 0; i < 4; ++i) {
        ll v = q[i];
        if (v < 0 || v >= (ll)n_nodes) ok = false;
    }
    return ok;
}

__device__ inline int load_idx(const void* p, ll e, bool is64) {
    return is64 ? (int)((const ll*)p)[e] : ((const int*)p)[e];
}

// ======================= fast path (N <= 65536) =======================

// merged setup: [0,PREP_B): x -> bf16 A-left AND fp8(exp(x)) table
//               [PREP_B,+128): W -> WT | rest: per-block dst histogram
__global__ __launch_bounds__(256) void k_setup(const float* __restrict__ x,
                                               unsigned short* __restrict__ A,
                                               unsigned char* __restrict__ expx8,
                                               const float* __restrict__ W,
                                               unsigned short* __restrict__ WT,
                                               const void* __restrict__ edst,
                                               int* __restrict__ bhist,
                                               int N, int E, int PREP_B, int WT_B) {
    __shared__ int hist[NBIN_MAX];
    int b = blockIdx.x, t = threadIdx.x;
    if (b < PREP_B) {
        int i = b * 256 + t;
        if (i < N * 32) {
            int n = i >> 5, c4 = i & 31;
            float4 v = *(const float4*)(x + (ll)n * D + c4 * 4);
            ushort4 o;
            o.x = f2bf(v.x); o.y = f2bf(v.y); o.z = f2bf(v.z); o.w = f2bf(v.w);
            *(ushort4*)(A + (ll)n * 256 + c4 * 4) = o;
            unsigned int p = pack_fp8x4(__expf(v.x), __expf(v.y), __expf(v.z), __expf(v.w));
            *(unsigned int*)(expx8 + (ll)n * 128 + c4 * 4) = p;
        }
        return;
    }
    b -= PREP_B;
    if (b < WT_B) {
        int idx = b * 256 + t;
        int k = idx >> 7, n = idx & 127;
        WT[n * 256 + k] = f2bf(W[idx]);
        return;
    }
    b -= WT_B;
    if (t < NBIN_MAX) hist[t] = 0;
    __syncthreads();
    bool is64 = idx_is_i64(edst, N);
    ll base = (ll)b * P1_EPB;
    int cnt = (int)min((ll)P1_EPB, (ll)E - base);
    for (int i = t; i < cnt; i += 256) {
        int d = load_idx(edst, base + i, is64);
        atomicAdd(&hist[d >> BINSHIFT], 1);
    }
    __syncthreads();
    if (t < NBIN_MAX) bhist[b * NBIN_MAX + t] = hist[t];
}

// sum per-block histograms + exclusive scan -> pbase/pcur; sentinels
__global__ __launch_bounds__(NBIN_MAX) void k_binscan(const int* __restrict__ bhist, int EB,
                                                      int* __restrict__ pbase,
                                                      int* __restrict__ pcur,
                                                      int* __restrict__ off, int E, int N) {
    __shared__ int s[NBIN_MAX];
    int t = threadIdx.x;
    int v = 0;
    for (int i = 0; i < EB; ++i) v += bhist[i * NBIN_MAX + t];
    s[t] = v;
    __syncthreads();
    for (int o = 1; o < NBIN_MAX; o <<= 1) {
        int xv = (t >= o) ? s[t - o] : 0;
        __syncthreads();
        s[t] += xv;
        __syncthreads();
    }
    pbase[t] = s[t] - v;
    pcur[t]  = s[t] - v;
    if (t == NBIN_MAX - 1) { pbase[NBIN_MAX] = s[t]; off[N] = E; }
}

// bin edges into coarse bins as packed (dst<<16)|src pairs
__global__ __launch_bounds__(256) void k_pass1b(const void* __restrict__ esrc,
                                                const void* __restrict__ edst,
                                                int* __restrict__ pcur,
                                                unsigned int* __restrict__ pairs,
                                                int E, int N) {
    __shared__ unsigned int sp[P1_EPB];   // 8 KB
    __shared__ int hist[NBIN_MAX];
    __shared__ int curs[NBIN_MAX];
    bool is64s = idx_is_i64(esrc, N);
    bool is64d = idx_is_i64(edst, N);
    int t = threadIdx.x;
    if (t < NBIN_MAX) hist[t] = 0;
    __syncthreads();
    ll base = (ll)blockIdx.x * P1_EPB;
    int cnt = (int)min((ll)P1_EPB, (ll)E - base);
    for (int i = t; i < cnt; i += 256) {
        unsigned int s = (unsigned int)load_idx(esrc, base + i, is64s);
        unsigned int d = (unsigned int)load_idx(edst, base + i, is64d);
        sp[i] = (d << 16) | s;
        atomicAdd(&hist[d >> BINSHIFT], 1);
    }
    __syncthreads();
    if (t < NBIN_MAX) curs[t] = hist[t] ? atomicAdd(&pcur[t], hist[t]) : 0;
    __syncthreads();
    for (int i = t; i < cnt; i += 256) {
        unsigned int p = sp[i];
        int b = p >> (16 + BINSHIFT);
        int pos = atomicAdd(&curs[b], 1);
        pairs[pos] = p;
    }
}

// per-bin: node-level CSR offsets + u16 src bucket (writes stay in an L2-hot window)
__global__ __launch_bounds__(256) void k_pass2(const unsigned int* __restrict__ pairs,
                                               const int* __restrict__ pbase,
                                               int* __restrict__ off,
                                               unsigned short* __restrict__ bucket, int N) {
    __shared__ int dhist[BINW];
    __shared__ int dscan[BINW];
    __shared__ int dcur[BINW];
    int b = blockIdx.x, t = threadIdx.x;
    int p0 = pbase[b], p1 = pbase[b + 1];
    int n0 = b << BINSHIFT;
    dhist[t] = 0;
    __syncthreads();
    for (int i = p0 + t; i < p1; i += 256)
        atomicAdd(&dhist[(pairs[i] >> 16) & (BINW - 1)], 1);
    __syncthreads();
    int h = dhist[t];
    dscan[t] = h;
    __syncthreads();
    for (int o = 1; o < BINW; o <<= 1) {
        int xv = (t >= o) ? dscan[t - o] : 0;
        __syncthreads();
        dscan[t] += xv;
        __syncthreads();
    }
    int ex = dscan[t] - h;    // exclusive prefix
    dcur[t] = ex;
    int lim = min(BINW, N - n0);
    if (t < lim) off[n0 + t] = p0 + ex;
    __syncthreads();
    for (int i = p0 + t; i < p1; i += 256) {
        unsigned int p = pairs[i];
        int dl = (p >> 16) & (BINW - 1);
        int pos = p0 + atomicAdd(&dcur[dl], 1);
        bucket[pos] = (unsigned short)(p & 0xFFFFu);
    }
}

// gather-side aggregation (r4 structure, fp8 payload): 1 wave per node,
// 16-lane x 8B coalesced fp8 row reads (128B/edge vs 256B for bf16),
// 2 gathers in flight per subgroup, no exp in the loop.
__global__ __launch_bounds__(256) void k_aggregate(const int* __restrict__ off,
                                                   const unsigned short* __restrict__ bucket,
                                                   const unsigned char* __restrict__ expx8,
                                                   unsigned short* __restrict__ A, int N) {
    int w = threadIdx.x >> 6, lane = threadIdx.x & 63;
    int n = blockIdx.x * 4 + w;
    if (n >= N) return;
    int start = off[n], end = off[n + 1];
    int sub = lane >> 4, c16 = lane & 15;
    const uint2* X = (const uint2*)expx8;   // row = 16 uint2 (128 fp8)
    float acc[8];
#pragma unroll
    for (int j = 0; j < 8; ++j) acc[j] = 0.f;
    int e = start + sub;
    for (; e + 4 < end; e += 8) {
        int s0 = bucket[e];
        int s1 = bucket[e + 4];
        uint2 v0 = X[(ll)s0 * 16 + c16];
        uint2 v1 = X[(ll)s1 * 16 + c16];
        acc_fp8x4(v0.x, acc);
        acc_fp8x4(v0.y, acc + 4);
        acc_fp8x4(v1.x, acc);
        acc_fp8x4(v1.y, acc + 4);
    }
    if (e < end) {
        int s0 = bucket[e];
        uint2 v0 = X[(ll)s0 * 16 + c16];
        acc_fp8x4(v0.x, acc);
        acc_fp8x4(v0.y, acc + 4);
    }
#pragma unroll
    for (int j = 0; j < 8; ++j) {
        acc[j] += __shfl_xor(acc[j], 16, 64);
        acc[j] += __shfl_xor(acc[j], 32, 64);
    }
    if (sub == 0) {
        int dg = end - start;
        unsigned int o[4];
#pragma unroll
        for (int k = 0; k < 4; ++k) {
            float a0 = (dg > 0) ? __logf(fmaxf(acc[2 * k],     EPS)) : 0.f;
            float a1 = (dg > 0) ? __logf(fmaxf(acc[2 * k + 1], EPS)) : 0.f;
            o[k] = (unsigned int)f2bf(a0) | ((unsigned int)f2bf(a1) << 16);
        }
        *(uint4*)(A + (ll)n * 256 + 128 + c16 * 8) = make_uint4(o[0], o[1], o[2], o[3]);
    }
}

// MFMA GEMM + LayerNorm + ReLU.  A (bf16 [N][256]) aliases out (f32 [N][128]):
// each block stages its own 64 rows into LDS before overwriting them.
__global__ __launch_bounds__(256) void k_gemm_mfma(
        const unsigned short* __restrict__ A,
        const unsigned short* __restrict__ WT,
        const float* __restrict__ bias,
        const float* __restrict__ gamma,
        const float* __restrict__ beta,
        float* __restrict__ out, int N) {
    __shared__ unsigned char sA[64 * 512];
    __shared__ float2 sPart[2][64];
    int t = threadIdx.x;
    int l = t & 63, w = t >> 6;
    int wr = w >> 1, wc = w & 1;
    int n0 = blockIdx.x * 64;

    const uint4* gA = (const uint4*)(A + (ll)n0 * 256);
#pragma unroll
    for (int i = 0; i < 8; ++i) {
        int c = i * 256 + t;
        int row = c >> 5, cc = c & 31;
        uint4 v = make_uint4(0u, 0u, 0u, 0u);
        if (n0 + row < N) v = gA[row * 32 + cc];
        *(uint4*)(sA + row * 512 + ((cc * 16) ^ ((row & 7) << 4))) = v;
    }
    __syncthreads();

    f32x4 acc[2][4];
#pragma unroll
    for (int m = 0; m < 2; ++m)
#pragma unroll
        for (int n = 0; n < 4; ++n) acc[m][n] = (f32x4){0.f, 0.f, 0.f, 0.f};

    const int lr = l & 15, lk = l >> 4;
    const int aswz = (lr & 7) << 4;
    const unsigned short* wbase = WT + (wc * 64 + lr) * 256 + lk * 8;

#pragma unroll
    for (int ks = 0; ks < 8; ++ks) {
        short8 a[2], b[4];
#pragma unroll
        for (int m = 0; m < 2; ++m) {
            int arow = wr * 32 + m * 16 + lr;
            a[m] = *(const short8*)(sA + arow * 512 + ((ks * 64 + lk * 16) ^ aswz));
        }
#pragma unroll
        for (int n = 0; n < 4; ++n)
            b[n] = *(const short8*)(wbase + n * 16 * 256 + ks * 32);
#pragma unroll
        for (int m = 0; m < 2; ++m)
#pragma unroll
            for (int n = 0; n < 4; ++n)
                acc[m][n] = __builtin_amdgcn_mfma_f32_16x16x32_bf16(a[m], b[n], acc[m][n], 0, 0, 0);
    }

    const int col_base = wc * 64 + lr;
    float bn[4], gn[4], ben[4];
#pragma unroll
    for (int n = 0; n < 4; ++n) {
        int col = col_base + n * 16;
        bn[n] = bias[col]; gn[n] = gamma[col]; ben[n] = beta[col];
    }
#pragma unroll
    for (int m = 0; m < 2; ++m) {
#pragma unroll
        for (int r = 0; r < 4; ++r) {
            float s = 0.f, q = 0.f;
#pragma unroll
            for (int n = 0; n < 4; ++n) {
                float v = acc[m][n][r] + bn[n];
                acc[m][n][r] = v;
                s += v; q += v * v;
            }
#pragma unroll
            for (int o = 1; o < 16; o <<= 1) {
                s += __shfl_xor(s, o, 64);
                q += __shfl_xor(q, o, 64);
            }
            if (lr == 0) {
                int rowl = wr * 32 + m * 16 + lk * 4 + r;
                sPart[wc][rowl] = make_float2(s, q);
            }
        }
    }
    __syncthreads();
#pragma unroll
    for (int m = 0; m < 2; ++m) {
#pragma unroll
        for (int r = 0; r < 4; ++r) {
            int rowl = wr * 32 + m * 16 + lk * 4 + r;
            float2 p0 = sPart[0][rowl], p1 = sPart[1][rowl];
            float ssum = p0.x + p1.x, qsum = p0.y + p1.y;
            float mean = ssum * (1.f / 128.f);
            float var  = qsum * (1.f / 128.f) - mean * mean;
            float rstd = rsqrtf(var + LN_EPS);
            int grow = n0 + rowl;
            if (grow < N) {
                float* op = out + (ll)grow * 128;
#pragma unroll
                for (int n = 0; n < 4; ++n) {
                    float y = (acc[m][n][r] - mean) * rstd * gn[n] + ben[n];
                    op[col_base + n * 16] = fmaxf(y, 0.f);
                }
            }
        }
    }
}

// ======================= mid path (counting sort) =======================

__global__ __launch_bounds__(256) void k_wt(const float* __restrict__ W,
                                            unsigned short* __restrict__ WT) {
    int idx = blockIdx.x * 256 + threadIdx.x;
    int k = idx >> 7, n = idx & 127;
    WT[n * 256 + k] = f2bf(W[idx]);
}

__global__ __launch_bounds__(256) void k_hist(const void* __restrict__ edst,
                                              int* __restrict__ deg, int E, int N) {
    bool is64 = idx_is_i64(edst, N);
    int i = blockIdx.x * 256 + threadIdx.x;
    if (i < E) atomicAdd(&deg[load_idx(edst, i, is64)], 1);
}

__global__ __launch_bounds__(256) void k_scanA(const int* __restrict__ deg,
                                               int* __restrict__ off,
                                               int* __restrict__ bsum, int N) {
    __shared__ int s[256];
    int b = blockIdx.x, t = threadIdx.x;
    int base = b * 1024 + t * 4;
    int v0 = 0, v1 = 0, v2 = 0, v3 = 0;
    if (base + 0 < N) v0 = deg[base + 0];
    if (base + 1 < N) v1 = deg[base + 1];
    if (base + 2 < N) v2 = deg[base + 2];
    if (base + 3 < N) v3 = deg[base + 3];
    int loc = v0 + v1 + v2 + v3;
    s[t] = loc;
    __syncthreads();
    for (int o = 1; o < 256; o <<= 1) {
        int xv = (t >= o) ? s[t - o] : 0;
        __syncthreads();
        s[t] += xv;
        __syncthreads();
    }
    int run = s[t] - loc;
    if (t == 255) bsum[b] = s[255];
    if (base + 0 < N) off[base + 0] = run; run += v0;
    if (base + 1 < N) off[base + 1] = run; run += v1;
    if (base + 2 < N) off[base + 2] = run; run += v2;
    if (base + 3 < N) off[base + 3] = run;
}

__global__ __launch_bounds__(256) void k_scanB(const int* __restrict__ bsum,
                                               int* __restrict__ bbase, int NB) {
    __shared__ int s[256];
    int t = threadIdx.x;
    int v = (t < NB) ? bsum[t] : 0;
    s[t] = v;
    __syncthreads();
    for (int o = 1; o < 256; o <<= 1) {
        int xv = (t >= o) ? s[t - o] : 0;
        __syncthreads();
        s[t] += xv;
        __syncthreads();
    }
    if (t < NB) bbase[t] = s[t] - v;
}

__global__ __launch_bounds__(256) void k_scanC(int* __restrict__ off,
                                               int* __restrict__ cur,
                                               const int* __restrict__ bbase, int N, int E) {
    int b = blockIdx.x, t = threadIdx.x;
    int add = bbase[b];
    int base = b * 1024 + t * 4;
#pragma unroll
    for (int i = 0; i < 4; ++i) {
        int idx = base + i;
        if (idx < N) {
            int o = off[idx] + add;
            off[idx] = o;
            cur[idx] = o;
        }
    }
    if (b == 0 && t == 0) off[N] = E;
}

__global__ __launch_bounds__(256) void k_scatter32(const void* __restrict__ esrc,
                                                   const void* __restrict__ edst,
                                                   int* __restrict__ cur,
                                                   unsigned short* __restrict__ bucket,
                                                   int E, int N) {
    bool is64s = idx_is_i64(esrc, N);
    bool is64d = idx_is_i64(edst, N);
    int i = blockIdx.x * 256 + threadIdx.x;
    if (i < E) {
        int s = load_idx(esrc, i, is64s);
        int d = load_idx(edst, i, is64d);
        int pos = atomicAdd(&cur[d], 1);
        bucket[pos] = (unsigned short)s;
    }
}

__global__ __launch_bounds__(128) void k_aggregate_mid(const float* __restrict__ x,
                                                       const unsigned short* __restrict__ bucket,
                                                       const int* __restrict__ off,
                                                       unsigned short* __restrict__ A, int N) {
    int n = blockIdx.x, t = threadIdx.x;
    int start = __builtin_amdgcn_readfirstlane(off[n]);
    int end   = __builtin_amdgcn_readfirstlane(off[n + 1]);
    float acc = 0.f;
    for (int e = start; e < end; ++e) {
        int s0 = bucket[e];
        acc += __expf(x[(ll)s0 * D + t]);
    }
    float agg = (end > start) ? __logf(fmaxf(acc, EPS)) : 0.f;
    A[(ll)n * 256 + t]       = f2bf(x[(ll)n * D + t]);
    A[(ll)n * 256 + 128 + t] = f2bf(agg);
}

// ======================= fallback (atomic) path =======================

__global__ __launch_bounds__(256) void scatter_expsum(
        const float* __restrict__ x, const void* __restrict__ esrc_raw,
        const void* __restrict__ edst_raw, float* __restrict__ sumexp,
        int* __restrict__ deg, int E, int N) {
    ll tid = (ll)blockIdx.x * blockDim.x + threadIdx.x;
    ll total = (ll)E * 32;
    if (tid >= total) return;
    bool is64 = idx_is_i64(esrc_raw, N);
    ll e = tid >> 5;
    int q = (int)(tid & 31);
    int s = load_idx(esrc_raw, e, is64);
    int d = load_idx(edst_raw, e, is64);
    const float4 v = *reinterpret_cast<const float4*>(x + (ll)s * D + q * 4);
    float* outp = sumexp + (ll)d * D + q * 4;
    atomicAdd(outp + 0, expf(v.x));
    atomicAdd(outp + 1, expf(v.y));
    atomicAdd(outp + 2, expf(v.z));
    atomicAdd(outp + 3, expf(v.w));
    if (q == 0) atomicAdd(deg + d, 1);
}

__global__ __launch_bounds__(128) void gemm_ln_relu_fb(
        const float* __restrict__ x, const float* __restrict__ sumexp,
        const int* __restrict__ deg, const float* __restrict__ W,
        const float* __restrict__ bias, const float* __restrict__ gamma,
        const float* __restrict__ beta, float* __restrict__ out) {
    const int n = blockIdx.x;
    const int t = threadIdx.x;
    __shared__ float v[2 * D];
    __shared__ float s_sum[2], s_sq[2];
    v[t] = x[(ll)n * D + t];
    float se = sumexp[(ll)n * D + t];
    v[D + t] = (deg[n] > 0) ? logf(fmaxf(se, EPS)) : 0.0f;
    __syncthreads();
    float acc = bias[t];
#pragma unroll 8
    for (int k = 0; k < 2 * D; ++k) acc += v[k] * W[k * D + t];
    float sum = acc, sq = acc * acc;
#pragma unroll
    for (int o = 32; o > 0; o >>= 1) {
        sum += __shfl_xor(sum, o, 64);
        sq  += __shfl_xor(sq, o, 64);
    }
    int w = t >> 6;
    if ((t & 63) == 0) { s_sum[w] = sum; s_sq[w] = sq; }
    __syncthreads();
    float mean = (s_sum[0] + s_sum[1]) * (1.0f / D);
    float var  = (s_sq[0] + s_sq[1]) * (1.0f / D) - mean * mean;
    float r = rsqrtf(var + LN_EPS);
    float y = (acc - mean) * r * gamma[t] + beta[t];
    out[(ll)n * D + t] = fmaxf(y, 0.0f);
}

// ======================= launch =======================

extern "C" void kernel_launch(void* const* d_in, const int* in_sizes, int n_in,
                              void* d_out, int out_size, void* d_ws, size_t ws_size,
                              hipStream_t stream) {
    const float* x     = (const float*)d_in[0];
    const void*  esrc  = d_in[1];
    const void*  edst  = d_in[2];
    const float* W     = (const float*)d_in[3];
    const float* bias  = (const float*)d_in[4];
    const float* gamma = (const float*)d_in[5];
    const float* beta  = (const float*)d_in[6];

    const int E = in_sizes[1];
    const int N = in_sizes[0] / D;
    float* out = (float*)d_out;
    unsigned short* A = (unsigned short*)d_out;   // A aliases out (split pipeline: safe)

    const int EB = (E + P1_EPB - 1) / P1_EPB;
    const int PREP_B = (N * 32 + 255) / 256;
    const int NBIN = (N + BINW - 1) >> BINSHIFT;

    // fast-path ws: expx8[N*128] u8 | off[N+1] | pbase[257] | pcur[256]
    //               | bhist[EB*256] | pairs[E] u32 | wt 64KB | bucket[E] u16
    size_t need_fast = (size_t)N * 128
                     + ((size_t)(N + 1) + 257 + 256 + (size_t)EB * NBIN_MAX + (size_t)E) * 4
                     + 65536 + (size_t)E * 2 + 64;
    const int NB = (N + 1023) / 1024;
    size_t need_mid = ((size_t)3 * N + 1 + 512 + 16384) * 4 + (size_t)E * 2 + 2;

    if (N <= 65536 && ws_size >= need_fast) {
        unsigned char* expx8 = (unsigned char*)d_ws;
        int* off             = (int*)(expx8 + (size_t)N * 128);
        int* pbase           = off + (N + 1);
        int* pcur            = pbase + 257;
        int* bhist           = pcur + 256;
        unsigned int* pairs  = (unsigned int*)(bhist + (size_t)EB * NBIN_MAX);
        unsigned short* wt   = (unsigned short*)((((size_t)(pairs + E)) + 15) & ~(size_t)15);
        unsigned short* bucket = wt + 32768;

        k_setup<<<PREP_B + 128 + EB, 256, 0, stream>>>(x, A, expx8, W, wt, edst, bhist,
                                                       N, E, PREP_B, 128);
        k_binscan<<<1, NBIN_MAX, 0, stream>>>(bhist, EB, pbase, pcur, off, E, N);
        k_pass1b<<<EB, 256, 0, stream>>>(esrc, edst, pcur, pairs, E, N);
        k_pass2<<<NBIN, 256, 0, stream>>>(pairs, pbase, off, bucket, N);
        k_aggregate<<<(N + 3) / 4, 256, 0, stream>>>(off, bucket, expx8, A, N);
        k_gemm_mfma<<<(N + 63) / 64, 256, 0, stream>>>(A, wt, bias, gamma, beta, out, N);
    } else if (N <= 65536 && ws_size >= need_mid && NB <= 256) {
        int* deg    = (int*)d_ws;
        int* off    = deg + N;
        int* cur    = off + (N + 1);
        int* bsum   = cur + N;
        int* bbase  = bsum + 256;
        unsigned short* wt = (unsigned short*)(bbase + 256);
        unsigned short* bucket = wt + 32768;

        hipMemsetAsync(deg, 0, (size_t)N * sizeof(int), stream);
        int eb = (E + 255) / 256;
        k_wt<<<128, 256, 0, stream>>>(W, wt);
        k_hist<<<eb, 256, 0, stream>>>(edst, deg, E, N);
        k_scanA<<<NB, 256, 0, stream>>>(deg, off, bsum, N);
        k_scanB<<<1, 256, 0, stream>>>(bsum, bbase, NB);
        k_scanC<<<NB, 256, 0, stream>>>(off, cur, bbase, N, E);
        k_scatter32<<<eb, 256, 0, stream>>>(esrc, edst, cur, bucket, E, N);
        k_aggregate_mid<<<N, 128, 0, stream>>>(x, bucket, off, A, N);
        k_gemm_mfma<<<(N + 63) / 64, 256, 0, stream>>>(A, wt, bias, gamma, beta, out, N);
    } else {
        float* sumexp = out;
        int* deg = (int*)d_ws;
        hipMemsetAsync(sumexp, 0, (size_t)N * D * sizeof(float), stream);
        hipMemsetAsync(deg, 0, (size_t)N * sizeof(int), stream);
        ll total = (ll)E * 32;
        int blocks = (int)((total + 255) / 256);
        scatter_expsum<<<blocks, 256, 0, stream>>>(x, esrc, edst, sumexp, deg, E, N);
        gemm_ln_relu_fb<<<N, D, 0, stream>>>(x, sumexp, deg, W, bias, gamma, beta, out);
    }
}

// Round 14
// 119.671 us; speedup vs baseline: 1.2897x; 1.2897x over previous
//
#include <hip/hip_runtime.h>
#include <math.h>

#define D 128
#define EPS 1e-30f
#define LN_EPS 1e-5f

#define BINSHIFT 8
#define BINW 256
#define NBIN_MAX 256
#define P1_EPB 2048

typedef long long ll;
typedef __attribute__((ext_vector_type(8))) short short8;
typedef __attribute__((ext_vector_type(4))) float f32x4;
typedef __attribute__((ext_vector_type(2))) float f32x2;

#if __has_builtin(__builtin_amdgcn_cvt_pk_f32_fp8) && __has_builtin(__builtin_amdgcn_cvt_pk_fp8_f32)
#define HAS_FP8_CVT 1
#else
#define HAS_FP8_CVT 0
#endif

// round-to-nearest-even f32 -> bf16
__device__ inline unsigned short f2bf(float f) {
    unsigned int u = __float_as_uint(f);
    u += 0x7FFF + ((u >> 16) & 1);
    return (unsigned short)(u >> 16);
}

__device__ inline float bf2f_lo(unsigned int w) { return __uint_as_float(w << 16); }
__device__ inline float bf2f_hi(unsigned int w) { return __uint_as_float(w & 0xFFFF0000u); }

// ---- fp8 e4m3 helpers (positive values only: exp(x) > 0) ----
__device__ inline unsigned int pack_fp8x4(float f0, float f1, float f2, float f3) {
#if HAS_FP8_CVT
    int p = 0;
    p = __builtin_amdgcn_cvt_pk_fp8_f32(fminf(f0, 440.f), fminf(f1, 440.f), p, false);
    p = __builtin_amdgcn_cvt_pk_fp8_f32(fminf(f2, 440.f), fminf(f3, 440.f), p, true);
    return (unsigned int)p;
#else
    auto enc = [](float f) -> unsigned int {
        if (!(f > 1.7e-3f)) return (unsigned int)max(0, min(7, (int)rintf(f * 512.f)));
        f = fminf(f, 440.f);
        unsigned int u = __float_as_uint(f);
        int ex = (int)((u >> 23) & 255) - 127;
        if (ex < -6) return (unsigned int)min(7, (int)rintf(f * 512.f));
        unsigned int mant = u & 0x7FFFFF;
        unsigned int r = (mant + 0x7FFFF + ((mant >> 20) & 1)) >> 20;
        return (unsigned int)(((ex + 7) << 3) + r);
    };
    return enc(f0) | (enc(f1) << 8) | (enc(f2) << 16) | (enc(f3) << 24);
#endif
}

__device__ inline void acc_fp8x4(unsigned int u, float* acc) {
#if HAS_FP8_CVT
    f32x2 a = __builtin_amdgcn_cvt_pk_f32_fp8((int)u, false);
    f32x2 b = __builtin_amdgcn_cvt_pk_f32_fp8((int)u, true);
    acc[0] += a[0]; acc[1] += a[1]; acc[2] += b[0]; acc[3] += b[1];
#else
    auto dec = [](unsigned int v) -> float {
        unsigned int e = (v >> 3) & 15, m = v & 7;
        if (e == 0) return (float)m * 0.001953125f;
        return __uint_as_float(((e + 120) << 23) | (m << 20));
    };
    acc[0] += dec(u & 255); acc[1] += dec((u >> 8) & 255);
    acc[2] += dec((u >> 16) & 255); acc[3] += dec(u >> 24);
#endif
}

// ---- index dtype sniffing: harness may hand us int32 or int64 indices ----
__device__ inline bool idx_is_i64(const void* p, int n_nodes) {
    const ll* q = (const ll*)p;
    bool ok = true;
#pragma unroll
    for (int i = 0; i < 4; ++i) {
        ll v = q[i];
        if (v < 0 || v >= (ll)n_nodes) ok = false;
    }
    return ok;
}

__device__ inline int load_idx(const void* p, ll e, bool is64) {
    return is64 ? (int)((const ll*)p)[e] : ((const int*)p)[e];
}

// ======================= fast path (N <= 65536) =======================

// merged setup: [0,PREP_B): x -> bf16 A-left AND fp8(exp(x)) table
//               [PREP_B,+128): W -> WT | rest: per-block dst histogram -> global bincnt
__global__ __launch_bounds__(256) void k_setup(const float* __restrict__ x,
                                               unsigned short* __restrict__ A,
                                               unsigned char* __restrict__ expx8,
                                               const float* __restrict__ W,
                                               unsigned short* __restrict__ WT,
                                               const void* __restrict__ edst,
                                               int* __restrict__ bincnt,
                                               int N, int E, int PREP_B, int WT_B) {
    __shared__ int hist[NBIN_MAX];
    int b = blockIdx.x, t = threadIdx.x;
    if (b < PREP_B) {
        int i = b * 256 + t;
        if (i < N * 32) {
            int n = i >> 5, c4 = i & 31;
            float4 v = *(const float4*)(x + (ll)n * D + c4 * 4);
            ushort4 o;
            o.x = f2bf(v.x); o.y = f2bf(v.y); o.z = f2bf(v.z); o.w = f2bf(v.w);
            *(ushort4*)(A + (ll)n * 256 + c4 * 4) = o;
            unsigned int p = pack_fp8x4(__expf(v.x), __expf(v.y), __expf(v.z), __expf(v.w));
            *(unsigned int*)(expx8 + (ll)n * 128 + c4 * 4) = p;
        }
        return;
    }
    b -= PREP_B;
    if (b < WT_B) {
        int idx = b * 256 + t;
        int k = idx >> 7, n = idx & 127;
        WT[n * 256 + k] = f2bf(W[idx]);
        return;
    }
    b -= WT_B;
    if (t < NBIN_MAX) hist[t] = 0;
    __syncthreads();
    bool is64 = idx_is_i64(edst, N);
    ll base = (ll)b * P1_EPB;
    int cnt = (int)min((ll)P1_EPB, (ll)E - base);
    for (int i = t; i < cnt; i += 256) {
        int d = load_idx(edst, base + i, is64);
        atomicAdd(&hist[d >> BINSHIFT], 1);
    }
    __syncthreads();
    if (t < NBIN_MAX && hist[t]) atomicAdd(&bincnt[t], hist[t]);
}

// exclusive scan of global bincnt -> pbase/pcur; sentinels (no EB loop)
__global__ __launch_bounds__(NBIN_MAX) void k_binscan(const int* __restrict__ bincnt,
                                                      int* __restrict__ pbase,
                                                      int* __restrict__ pcur,
                                                      int* __restrict__ off, int E, int N) {
    __shared__ int s[NBIN_MAX];
    int t = threadIdx.x;
    int v = bincnt[t];
    s[t] = v;
    __syncthreads();
    for (int o = 1; o < NBIN_MAX; o <<= 1) {
        int xv = (t >= o) ? s[t - o] : 0;
        __syncthreads();
        s[t] += xv;
        __syncthreads();
    }
    pbase[t] = s[t] - v;
    pcur[t]  = s[t] - v;
    if (t == NBIN_MAX - 1) { pbase[NBIN_MAX] = s[t]; off[N] = E; }
}

// bin edges into coarse bins as packed (dst<<16)|src pairs
__global__ __launch_bounds__(256) void k_pass1b(const void* __restrict__ esrc,
                                                const void* __restrict__ edst,
                                                int* __restrict__ pcur,
                                                unsigned int* __restrict__ pairs,
                                                int E, int N) {
    __shared__ unsigned int sp[P1_EPB];   // 8 KB
    __shared__ int hist[NBIN_MAX];
    __shared__ int curs[NBIN_MAX];
    bool is64s = idx_is_i64(esrc, N);
    bool is64d = idx_is_i64(edst, N);
    int t = threadIdx.x;
    if (t < NBIN_MAX) hist[t] = 0;
    __syncthreads();
    ll base = (ll)blockIdx.x * P1_EPB;
    int cnt = (int)min((ll)P1_EPB, (ll)E - base);
    for (int i = t; i < cnt; i += 256) {
        unsigned int s = (unsigned int)load_idx(esrc, base + i, is64s);
        unsigned int d = (unsigned int)load_idx(edst, base + i, is64d);
        sp[i] = (d << 16) | s;
        atomicAdd(&hist[d >> BINSHIFT], 1);
    }
    __syncthreads();
    if (t < NBIN_MAX) curs[t] = hist[t] ? atomicAdd(&pcur[t], hist[t]) : 0;
    __syncthreads();
    for (int i = t; i < cnt; i += 256) {
        unsigned int p = sp[i];
        int b = p >> (16 + BINSHIFT);
        int pos = atomicAdd(&curs[b], 1);
        pairs[pos] = p;
    }
}

// per-bin: node-level CSR offsets + u16 src bucket (writes stay in an L2-hot window)
__global__ __launch_bounds__(256) void k_pass2(const unsigned int* __restrict__ pairs,
                                               const int* __restrict__ pbase,
                                               int* __restrict__ off,
                                               unsigned short* __restrict__ bucket, int N) {
    __shared__ int dhist[BINW];
    __shared__ int dscan[BINW];
    __shared__ int dcur[BINW];
    int b = blockIdx.x, t = threadIdx.x;
    int p0 = pbase[b], p1 = pbase[b + 1];
    int n0 = b << BINSHIFT;
    dhist[t] = 0;
    __syncthreads();
    for (int i = p0 + t; i < p1; i += 256)
        atomicAdd(&dhist[(pairs[i] >> 16) & (BINW - 1)], 1);
    __syncthreads();
    int h = dhist[t];
    dscan[t] = h;
    __syncthreads();
    for (int o = 1; o < BINW; o <<= 1) {
        int xv = (t >= o) ? dscan[t - o] : 0;
        __syncthreads();
        dscan[t] += xv;
        __syncthreads();
    }
    int ex = dscan[t] - h;    // exclusive prefix
    dcur[t] = ex;
    int lim = min(BINW, N - n0);
    if (t < lim) off[n0 + t] = p0 + ex;
    __syncthreads();
    for (int i = p0 + t; i < p1; i += 256) {
        unsigned int p = pairs[i];
        int dl = (p >> 16) & (BINW - 1);
        int pos = p0 + atomicAdd(&dcur[dl], 1);
        bucket[pos] = (unsigned short)(p & 0xFFFFu);
    }
}

// gather-side aggregation (r4 structure, fp8 payload): 1 wave per node,
// 16-lane x 8B coalesced fp8 row reads (128B/edge vs 256B for bf16),
// 2 gathers in flight per subgroup, no exp in the loop.
__global__ __launch_bounds__(256) void k_aggregate(const int* __restrict__ off,
                                                   const unsigned short* __restrict__ bucket,
                                                   const unsigned char* __restrict__ expx8,
                                                   unsigned short* __restrict__ A, int N) {
    int w = threadIdx.x >> 6, lane = threadIdx.x & 63;
    int n = blockIdx.x * 4 + w;
    if (n >= N) return;
    int start = off[n], end = off[n + 1];
    int sub = lane >> 4, c16 = lane & 15;
    const uint2* X = (const uint2*)expx8;   // row = 16 uint2 (128 fp8)
    float acc[8];
#pragma unroll
    for (int j = 0; j < 8; ++j) acc[j] = 0.f;
    int e = start + sub;
    for (; e + 4 < end; e += 8) {
        int s0 = bucket[e];
        int s1 = bucket[e + 4];
        uint2 v0 = X[(ll)s0 * 16 + c16];
        uint2 v1 = X[(ll)s1 * 16 + c16];
        acc_fp8x4(v0.x, acc);
        acc_fp8x4(v0.y, acc + 4);
        acc_fp8x4(v1.x, acc);
        acc_fp8x4(v1.y, acc + 4);
    }
    if (e < end) {
        int s0 = bucket[e];
        uint2 v0 = X[(ll)s0 * 16 + c16];
        acc_fp8x4(v0.x, acc);
        acc_fp8x4(v0.y, acc + 4);
    }
#pragma unroll
    for (int j = 0; j < 8; ++j) {
        acc[j] += __shfl_xor(acc[j], 16, 64);
        acc[j] += __shfl_xor(acc[j], 32, 64);
    }
    if (sub == 0) {
        int dg = end - start;
        unsigned int o[4];
#pragma unroll
        for (int k = 0; k < 4; ++k) {
            float a0 = (dg > 0) ? __logf(fmaxf(acc[2 * k],     EPS)) : 0.f;
            float a1 = (dg > 0) ? __logf(fmaxf(acc[2 * k + 1], EPS)) : 0.f;
            o[k] = (unsigned int)f2bf(a0) | ((unsigned int)f2bf(a1) << 16);
        }
        *(uint4*)(A + (ll)n * 256 + 128 + c16 * 8) = make_uint4(o[0], o[1], o[2], o[3]);
    }
}

// MFMA GEMM + LayerNorm + ReLU.  A (bf16 [N][256]) aliases out (f32 [N][128]):
// each block stages its own 64 rows into LDS before overwriting them.
__global__ __launch_bounds__(256) void k_gemm_mfma(
        const unsigned short* __restrict__ A,
        const unsigned short* __restrict__ WT,
        const float* __restrict__ bias,
        const float* __restrict__ gamma,
        const float* __restrict__ beta,
        float* __restrict__ out, int N) {
    __shared__ unsigned char sA[64 * 512];
    __shared__ float2 sPart[2][64];
    int t = threadIdx.x;
    int l = t & 63, w = t >> 6;
    int wr = w >> 1, wc = w & 1;
    int n0 = blockIdx.x * 64;

    const uint4* gA = (const uint4*)(A + (ll)n0 * 256);
#pragma unroll
    for (int i = 0; i < 8; ++i) {
        int c = i * 256 + t;
        int row = c >> 5, cc = c & 31;
        uint4 v = make_uint4(0u, 0u, 0u, 0u);
        if (n0 + row < N) v = gA[row * 32 + cc];
        *(uint4*)(sA + row * 512 + ((cc * 16) ^ ((row & 7) << 4))) = v;
    }
    __syncthreads();

    f32x4 acc[2][4];
#pragma unroll
    for (int m = 0; m < 2; ++m)
#pragma unroll
        for (int n = 0; n < 4; ++n) acc[m][n] = (f32x4){0.f, 0.f, 0.f, 0.f};

    const int lr = l & 15, lk = l >> 4;
    const int aswz = (lr & 7) << 4;
    const unsigned short* wbase = WT + (wc * 64 + lr) * 256 + lk * 8;

#pragma unroll
    for (int ks = 0; ks < 8; ++ks) {
        short8 a[2], b[4];
#pragma unroll
        for (int m = 0; m < 2; ++m) {
            int arow = wr * 32 + m * 16 + lr;
            a[m] = *(const short8*)(sA + arow * 512 + ((ks * 64 + lk * 16) ^ aswz));
        }
#pragma unroll
        for (int n = 0; n < 4; ++n)
            b[n] = *(const short8*)(wbase + n * 16 * 256 + ks * 32);
#pragma unroll
        for (int m = 0; m < 2; ++m)
#pragma unroll
            for (int n = 0; n < 4; ++n)
                acc[m][n] = __builtin_amdgcn_mfma_f32_16x16x32_bf16(a[m], b[n], acc[m][n], 0, 0, 0);
    }

    const int col_base = wc * 64 + lr;
    float bn[4], gn[4], ben[4];
#pragma unroll
    for (int n = 0; n < 4; ++n) {
        int col = col_base + n * 16;
        bn[n] = bias[col]; gn[n] = gamma[col]; ben[n] = beta[col];
    }
#pragma unroll
    for (int m = 0; m < 2; ++m) {
#pragma unroll
        for (int r = 0; r < 4; ++r) {
            float s = 0.f, q = 0.f;
#pragma unroll
            for (int n = 0; n < 4; ++n) {
                float v = acc[m][n][r] + bn[n];
                acc[m][n][r] = v;
                s += v; q += v * v;
            }
#pragma unroll
            for (int o = 1; o < 16; o <<= 1) {
                s += __shfl_xor(s, o, 64);
                q += __shfl_xor(q, o, 64);
            }
            if (lr == 0) {
                int rowl = wr * 32 + m * 16 + lk * 4 + r;
                sPart[wc][rowl] = make_float2(s, q);
            }
        }
    }
    __syncthreads();
#pragma unroll
    for (int m = 0; m < 2; ++m) {
#pragma unroll
        for (int r = 0; r < 4; ++r) {
            int rowl = wr * 32 + m * 16 + lk * 4 + r;
            float2 p0 = sPart[0][rowl], p1 = sPart[1][rowl];
            float ssum = p0.x + p1.x, qsum = p0.y + p1.y;
            float mean = ssum * (1.f / 128.f);
            float var  = qsum * (1.f / 128.f) - mean * mean;
            float rstd = rsqrtf(var + LN_EPS);
            int grow = n0 + rowl;
            if (grow < N) {
                float* op = out + (ll)grow * 128;
#pragma unroll
                for (int n = 0; n < 4; ++n) {
                    float y = (acc[m][n][r] - mean) * rstd * gn[n] + ben[n];
                    op[col_base + n * 16] = fmaxf(y, 0.f);
                }
            }
        }
    }
}

// ======================= mid path (counting sort) =======================

__global__ __launch_bounds__(256) void k_wt(const float* __restrict__ W,
                                            unsigned short* __restrict__ WT) {
    int idx = blockIdx.x * 256 + threadIdx.x;
    int k = idx >> 7, n = idx & 127;
    WT[n * 256 + k] = f2bf(W[idx]);
}

__global__ __launch_bounds__(256) void k_hist(const void* __restrict__ edst,
                                              int* __restrict__ deg, int E, int N) {
    bool is64 = idx_is_i64(edst, N);
    int i = blockIdx.x * 256 + threadIdx.x;
    if (i < E) atomicAdd(&deg[load_idx(edst, i, is64)], 1);
}

__global__ __launch_bounds__(256) void k_scanA(const int* __restrict__ deg,
                                               int* __restrict__ off,
                                               int* __restrict__ bsum, int N) {
    __shared__ int s[256];
    int b = blockIdx.x, t = threadIdx.x;
    int base = b * 1024 + t * 4;
    int v0 = 0, v1 = 0, v2 = 0, v3 = 0;
    if (base + 0 < N) v0 = deg[base + 0];
    if (base + 1 < N) v1 = deg[base + 1];
    if (base + 2 < N) v2 = deg[base + 2];
    if (base + 3 < N) v3 = deg[base + 3];
    int loc = v0 + v1 + v2 + v3;
    s[t] = loc;
    __syncthreads();
    for (int o = 1; o < 256; o <<= 1) {
        int xv = (t >= o) ? s[t - o] : 0;
        __syncthreads();
        s[t] += xv;
        __syncthreads();
    }
    int run = s[t] - loc;
    if (t == 255) bsum[b] = s[255];
    if (base + 0 < N) off[base + 0] = run; run += v0;
    if (base + 1 < N) off[base + 1] = run; run += v1;
    if (base + 2 < N) off[base + 2] = run; run += v2;
    if (base + 3 < N) off[base + 3] = run;
}

__global__ __launch_bounds__(256) void k_scanB(const int* __restrict__ bsum,
                                               int* __restrict__ bbase, int NB) {
    __shared__ int s[256];
    int t = threadIdx.x;
    int v = (t < NB) ? bsum[t] : 0;
    s[t] = v;
    __syncthreads();
    for (int o = 1; o < 256; o <<= 1) {
        int xv = (t >= o) ? s[t - o] : 0;
        __syncthreads();
        s[t] += xv;
        __syncthreads();
    }
    if (t < NB) bbase[t] = s[t] - v;
}

__global__ __launch_bounds__(256) void k_scanC(int* __restrict__ off,
                                               int* __restrict__ cur,
                                               const int* __restrict__ bbase, int N, int E) {
    int b = blockIdx.x, t = threadIdx.x;
    int add = bbase[b];
    int base = b * 1024 + t * 4;
#pragma unroll
    for (int i = 0; i < 4; ++i) {
        int idx = base + i;
        if (idx < N) {
            int o = off[idx] + add;
            off[idx] = o;
            cur[idx] = o;
        }
    }
    if (b == 0 && t == 0) off[N] = E;
}

__global__ __launch_bounds__(256) void k_scatter32(const void* __restrict__ esrc,
                                                   const void* __restrict__ edst,
                                                   int* __restrict__ cur,
                                                   unsigned short* __restrict__ bucket,
                                                   int E, int N) {
    bool is64s = idx_is_i64(esrc, N);
    bool is64d = idx_is_i64(edst, N);
    int i = blockIdx.x * 256 + threadIdx.x;
    if (i < E) {
        int s = load_idx(esrc, i, is64s);
        int d = load_idx(edst, i, is64d);
        int pos = atomicAdd(&cur[d], 1);
        bucket[pos] = (unsigned short)s;
    }
}

__global__ __launch_bounds__(128) void k_aggregate_mid(const float* __restrict__ x,
                                                       const unsigned short* __restrict__ bucket,
                                                       const int* __restrict__ off,
                                                       unsigned short* __restrict__ A, int N) {
    int n = blockIdx.x, t = threadIdx.x;
    int start = __builtin_amdgcn_readfirstlane(off[n]);
    int end   = __builtin_amdgcn_readfirstlane(off[n + 1]);
    float acc = 0.f;
    for (int e = start; e < end; ++e) {
        int s0 = bucket[e];
        acc += __expf(x[(ll)s0 * D + t]);
    }
    float agg = (end > start) ? __logf(fmaxf(acc, EPS)) : 0.f;
    A[(ll)n * 256 + t]       = f2bf(x[(ll)n * D + t]);
    A[(ll)n * 256 + 128 + t] = f2bf(agg);
}

// ======================= fallback (atomic) path =======================

__global__ __launch_bounds__(256) void scatter_expsum(
        const float* __restrict__ x, const void* __restrict__ esrc_raw,
        const void* __restrict__ edst_raw, float* __restrict__ sumexp,
        int* __restrict__ deg, int E, int N) {
    ll tid = (ll)blockIdx.x * blockDim.x + threadIdx.x;
    ll total = (ll)E * 32;
    if (tid >= total) return;
    bool is64 = idx_is_i64(esrc_raw, N);
    ll e = tid >> 5;
    int q = (int)(tid & 31);
    int s = load_idx(esrc_raw, e, is64);
    int d = load_idx(edst_raw, e, is64);
    const float4 v = *reinterpret_cast<const float4*>(x + (ll)s * D + q * 4);
    float* outp = sumexp + (ll)d * D + q * 4;
    atomicAdd(outp + 0, expf(v.x));
    atomicAdd(outp + 1, expf(v.y));
    atomicAdd(outp + 2, expf(v.z));
    atomicAdd(outp + 3, expf(v.w));
    if (q == 0) atomicAdd(deg + d, 1);
}

__global__ __launch_bounds__(128) void gemm_ln_relu_fb(
        const float* __restrict__ x, const float* __restrict__ sumexp,
        const int* __restrict__ deg, const float* __restrict__ W,
        const float* __restrict__ bias, const float* __restrict__ gamma,
        const float* __restrict__ beta, float* __restrict__ out) {
    const int n = blockIdx.x;
    const int t = threadIdx.x;
    __shared__ float v[2 * D];
    __shared__ float s_sum[2], s_sq[2];
    v[t] = x[(ll)n * D + t];
    float se = sumexp[(ll)n * D + t];
    v[D + t] = (deg[n] > 0) ? logf(fmaxf(se, EPS)) : 0.0f;
    __syncthreads();
    float acc = bias[t];
#pragma unroll 8
    for (int k = 0; k < 2 * D; ++k) acc += v[k] * W[k * D + t];
    float sum = acc, sq = acc * acc;
#pragma unroll
    for (int o = 32; o > 0; o >>= 1) {
        sum += __shfl_xor(sum, o, 64);
        sq  += __shfl_xor(sq, o, 64);
    }
    int w = t >> 6;
    if ((t & 63) == 0) { s_sum[w] = sum; s_sq[w] = sq; }
    __syncthreads();
    float mean = (s_sum[0] + s_sum[1]) * (1.0f / D);
    float var  = (s_sq[0] + s_sq[1]) * (1.0f / D) - mean * mean;
    float r = rsqrtf(var + LN_EPS);
    float y = (acc - mean) * r * gamma[t] + beta[t];
    out[(ll)n * D + t] = fmaxf(y, 0.0f);
}

// ======================= launch =======================

extern "C" void kernel_launch(void* const* d_in, const int* in_sizes, int n_in,
                              void* d_out, int out_size, void* d_ws, size_t ws_size,
                              hipStream_t stream) {
    const float* x     = (const float*)d_in[0];
    const void*  esrc  = d_in[1];
    const void*  edst  = d_in[2];
    const float* W     = (const float*)d_in[3];
    const float* bias  = (const float*)d_in[4];
    const float* gamma = (const float*)d_in[5];
    const float* beta  = (const float*)d_in[6];

    const int E = in_sizes[1];
    const int N = in_sizes[0] / D;
    float* out = (float*)d_out;
    unsigned short* A = (unsigned short*)d_out;   // A aliases out (split pipeline: safe)

    const int EB = (E + P1_EPB - 1) / P1_EPB;
    const int PREP_B = (N * 32 + 255) / 256;
    const int NBIN = (N + BINW - 1) >> BINSHIFT;

    // fast-path ws: expx8[N*128] u8 | off[N+1] | pbase[257] | pcur[256]
    //               | bincnt[256] | pairs[E] u32 | wt 64KB | bucket[E] u16
    size_t need_fast = (size_t)N * 128
                     + ((size_t)(N + 1) + 257 + 256 + 256 + (size_t)E) * 4
                     + 65536 + (size_t)E * 2 + 64;
    const int NB = (N + 1023) / 1024;
    size_t need_mid = ((size_t)3 * N + 1 + 512 + 16384) * 4 + (size_t)E * 2 + 2;

    if (N <= 65536 && ws_size >= need_fast) {
        unsigned char* expx8 = (unsigned char*)d_ws;
        int* off             = (int*)(expx8 + (size_t)N * 128);
        int* pbase           = off + (N + 1);
        int* pcur            = pbase + 257;
        int* bincnt          = pcur + 256;
        unsigned int* pairs  = (unsigned int*)(bincnt + 256);
        unsigned short* wt   = (unsigned short*)((((size_t)(pairs + E)) + 15) & ~(size_t)15);
        unsigned short* bucket = wt + 32768;

        hipMemsetAsync(bincnt, 0, NBIN_MAX * sizeof(int), stream);
        k_setup<<<PREP_B + 128 + EB, 256, 0, stream>>>(x, A, expx8, W, wt, edst, bincnt,
                                                       N, E, PREP_B, 128);
        k_binscan<<<1, NBIN_MAX, 0, stream>>>(bincnt, pbase, pcur, off, E, N);
        k_pass1b<<<EB, 256, 0, stream>>>(esrc, edst, pcur, pairs, E, N);
        k_pass2<<<NBIN, 256, 0, stream>>>(pairs, pbase, off, bucket, N);
        k_aggregate<<<(N + 3) / 4, 256, 0, stream>>>(off, bucket, expx8, A, N);
        k_gemm_mfma<<<(N + 63) / 64, 256, 0, stream>>>(A, wt, bias, gamma, beta, out, N);
    } else if (N <= 65536 && ws_size >= need_mid && NB <= 256) {
        int* deg    = (int*)d_ws;
        int* off    = deg + N;
        int* cur    = off + (N + 1);
        int* bsum   = cur + N;
        int* bbase  = bsum + 256;
        unsigned short* wt = (unsigned short*)(bbase + 256);
        unsigned short* bucket = wt + 32768;

        hipMemsetAsync(deg, 0, (size_t)N * sizeof(int), stream);
        int eb = (E + 255) / 256;
        k_wt<<<128, 256, 0, stream>>>(W, wt);
        k_hist<<<eb, 256, 0, stream>>>(edst, deg, E, N);
        k_scanA<<<NB, 256, 0, stream>>>(deg, off, bsum, N);
        k_scanB<<<1, 256, 0, stream>>>(bsum, bbase, NB);
        k_scanC<<<NB, 256, 0, stream>>>(off, cur, bbase, N, E);
        k_scatter32<<<eb, 256, 0, stream>>>(esrc, edst, cur, bucket, E, N);
        k_aggregate_mid<<<N, 128, 0, stream>>>(x, bucket, off, A, N);
        k_gemm_mfma<<<(N + 63) / 64, 256, 0, stream>>>(A, wt, bias, gamma, beta, out, N);
    } else {
        float* sumexp = out;
        int* deg = (int*)d_ws;
        hipMemsetAsync(sumexp, 0, (size_t)N * D * sizeof(float), stream);
        hipMemsetAsync(deg, 0, (size_t)N * sizeof(int), stream);
        ll total = (ll)E * 32;
        int blocks = (int)((total + 255) / 256);
        scatter_expsum<<<blocks, 256, 0, stream>>>(x, esrc, edst, sumexp, deg, E, N);
        gemm_ln_relu_fb<<<N, D, 0, stream>>>(x, sumexp, deg, W, bias, gamma, beta, out);
    }
}